// Round 6
// baseline (1143.211 us; speedup 1.0000x reference)
//
#include <hip/hip_runtime.h>
#include <hip/hip_bf16.h>

#define NN 100000
#define EE 1600000
#define HH 128
#define OUTC 10
#define BB 500
#define GSZ 200
#define LDA 136   // 128 + 8 bf16 pad

#define NBKT 782          // ceil(NN/128)
#define BCAP 2560
#define EPB 4096
#define NTILE64 1563      // ceil(NN/64)

typedef float f32x4 __attribute__((ext_vector_type(4)));
typedef __bf16 bf16x8 __attribute__((ext_vector_type(8)));

__device__ __forceinline__ float b2f(unsigned short u){
    unsigned int x = ((unsigned int)u) << 16;
    return __builtin_bit_cast(float, x);
}
__device__ __forceinline__ unsigned short f2b(float f){
    __hip_bfloat16 h = __float2bfloat16(f);
    return __builtin_bit_cast(unsigned short, h);
}

// ---------------- CSR build: bucketed counting sort ----------------
__global__ __launch_bounds__(256) void k_bucket(const int* __restrict__ src, const int* __restrict__ dst,
                                                int* __restrict__ bucket_cursor, unsigned int* __restrict__ ebuf){
    __shared__ unsigned int val[EPB];
    __shared__ unsigned short bkt[EPB];
    __shared__ int hist[NBKT];
    int t = threadIdx.x;
    int e0 = blockIdx.x * EPB;
    for (int i = t; i < NBKT; i += 256) hist[i] = 0;
    __syncthreads();
    for (int i = t; i < EPB; i += 256){
        int e = e0 + i;
        if (e < EE){
            int d = dst[e];
            int b = d >> 7;
            val[i] = ((unsigned)src[e] << 7) | (unsigned)(d & 127);
            bkt[i] = (unsigned short)b;
            atomicAdd(&hist[b], 1);
        } else {
            bkt[i] = 0xffff;
        }
    }
    __syncthreads();
    for (int i = t; i < NBKT; i += 256){
        int c = hist[i];
        hist[i] = c ? atomicAdd(&bucket_cursor[i], c) : 0;
    }
    __syncthreads();
    for (int i = t; i < EPB; i += 256){
        unsigned short b = bkt[i];
        if (b != 0xffff){
            int pos = atomicAdd(&hist[b], 1);
            if (pos < BCAP) ebuf[(int)b * BCAP + pos] = val[i];
        }
    }
}

__global__ __launch_bounds__(1024) void k_bscan(const int* __restrict__ bucket_cursor,
                                                int* __restrict__ bucket_base, int* __restrict__ row_ptr){
    __shared__ int tmp[1024];
    int t = threadIdx.x;
    int v = (t < NBKT) ? min(bucket_cursor[t], BCAP) : 0;
    tmp[t] = v; __syncthreads();
    for (int off = 1; off < 1024; off <<= 1){
        int a = (t >= off) ? tmp[t - off] : 0;
        __syncthreads();
        tmp[t] += a;
        __syncthreads();
    }
    if (t < NBKT) bucket_base[t + 1] = tmp[t];
    if (t == 0){ bucket_base[0] = 0; row_ptr[NN] = EE; }
}

__global__ __launch_bounds__(256) void k_csr(const int* __restrict__ bucket_cursor, const int* __restrict__ bucket_base,
                                             const unsigned int* __restrict__ ebuf,
                                             int* __restrict__ row_ptr, int* __restrict__ col){
    __shared__ int cnt[128];
    __shared__ int pfx[128];
    int b = blockIdx.x;
    int t = threadIdx.x;
    int c    = min(bucket_cursor[b], BCAP);
    int base = bucket_base[b];
    if (t < 128) cnt[t] = 0;
    __syncthreads();
    const unsigned int* eb = ebuf + (size_t)b * BCAP;
    for (int i = t; i < c; i += 256) atomicAdd(&cnt[eb[i] & 127], 1);
    __syncthreads();
    if (t == 0){
        int run = 0;
        for (int i = 0; i < 128; ++i){ pfx[i] = run; run += cnt[i]; }
    }
    __syncthreads();
    int node0 = b * 128;
    if (t < 128 && node0 + t < NN) row_ptr[node0 + t] = base + pfx[t];
    if (t < 128) cnt[t] = pfx[t];
    __syncthreads();
    for (int i = t; i < c; i += 256){
        unsigned int v = eb[i];
        int pos = atomicAdd(&cnt[v & 127], 1);
        col[base + pos] = (int)(v >> 7);
    }
}

// ---------------- weight prep: Wbf[w][n][k] = bf16(W_w[k][n]) ----------------
__global__ __launch_bounds__(256) void k_prep(const float* __restrict__ preW1, const float* __restrict__ preW2,
                                              const float* __restrict__ mlpW1, const float* __restrict__ mlpW2,
                                              unsigned short* __restrict__ Wbf){
    int idx = blockIdx.x*256 + threadIdx.x;   // 8*128*128
    int w = idx >> 14;
    int n = (idx >> 7) & 127;
    int k = idx & 127;
    const float* src;
    if      (w == 0) src = preW1;
    else if (w == 1) src = preW2;
    else if (w <  5) src = mlpW1 + (w-2)*16384;
    else             src = mlpW2 + (w-5)*16384;
    Wbf[idx] = f2b(src[k*128 + n]);
}

// ---------------- input: cast fp32->bf16 + pool reps[0] + zero G[1..4] ----------------
__global__ __launch_bounds__(256) void k_input(const float* __restrict__ x, unsigned short* __restrict__ hA,
                                               float* __restrict__ G){
    __shared__ float r0[256], r1[256];
    int t = threadIdx.x;
    int f2 = t & 63;
    int rg = t >> 6;
    int g  = blockIdx.x;
    if (t < 128){
        #pragma unroll
        for (int k = 1; k < 5; ++k) G[(size_t)k*BB*128 + g*128 + t] = 0.f;
    }
    float a0 = 0.f, a1 = 0.f;
    for (int i = rg; i < GSZ; i += 4){
        int node = g*GSZ + i;
        float2 v = *(const float2*)(x + (size_t)node*128 + f2*2);
        a0 += v.x; a1 += v.y;
        unsigned int o = (unsigned)f2b(v.x) | ((unsigned)f2b(v.y) << 16);
        ((unsigned int*)hA)[(size_t)node*64 + f2] = o;
    }
    r0[t] = a0; r1[t] = a1;
    __syncthreads();
    if (t < 64){
        float s0 = r0[t] + r0[t+64] + r0[t+128] + r0[t+192];
        float s1 = r1[t] + r1[t+64] + r1[t+128] + r1[t+192];
        float2 v; v.x = s0; v.y = s1;
        *(float2*)(G + g*128 + t*2) = v;
    }
}

// ---------------- aggregation (round-3 proven version) ----------------
__device__ __forceinline__ void acc_u32(float* a, unsigned int v, int j){
    a[j]   += __builtin_bit_cast(float, v << 16);
    a[j+1] += __builtin_bit_cast(float, v & 0xffff0000u);
}
__device__ __forceinline__ void acc_u4(float* a, uint4 v){
    acc_u32(a, v.x, 0); acc_u32(a, v.y, 2); acc_u32(a, v.z, 4); acc_u32(a, v.w, 6);
}

__global__ __launch_bounds__(256) void k_agg(const int* __restrict__ row_ptr, const int* __restrict__ col,
                                             const unsigned short* __restrict__ h,
                                             const float* __restrict__ eps, int l,
                                             unsigned short* __restrict__ pooled){
    int lane = threadIdx.x & 63;
    int wv   = threadIdx.x >> 6;
    int n    = blockIdx.x*4 + wv;
    int q = lane >> 4;
    int u = lane & 15;
    int beg = row_ptr[n], end = row_ptr[n+1];
    float a[8];
    #pragma unroll
    for (int j = 0; j < 8; ++j) a[j] = 0.f;

    int e = beg;
    for (; e + 16 <= end; e += 16){
        int c0 = col[e      + q];
        int c1 = col[e + 4  + q];
        int c2 = col[e + 8  + q];
        int c3 = col[e + 12 + q];
        uint4 v0 = *(const uint4*)(h + (size_t)c0*128 + u*8);
        uint4 v1 = *(const uint4*)(h + (size_t)c1*128 + u*8);
        uint4 v2 = *(const uint4*)(h + (size_t)c2*128 + u*8);
        uint4 v3 = *(const uint4*)(h + (size_t)c3*128 + u*8);
        acc_u4(a, v0); acc_u4(a, v1); acc_u4(a, v2); acc_u4(a, v3);
    }
    for (; e + 4 <= end; e += 4){
        int c = col[e + q];
        uint4 v = *(const uint4*)(h + (size_t)c*128 + u*8);
        acc_u4(a, v);
    }
    if (e < end){
        if (e + q < end){
            int c = col[e + q];
            uint4 v = *(const uint4*)(h + (size_t)c*128 + u*8);
            acc_u4(a, v);
        }
    }
    #pragma unroll
    for (int j = 0; j < 8; ++j){
        a[j] += __shfl_xor(a[j], 16, 64);
        a[j] += __shfl_xor(a[j], 32, 64);
    }
    if (q == 0){
        float ep = 1.0f + eps[l];
        uint4 hs = *(const uint4*)(h + (size_t)n*128 + u*8);
        a[0] += ep * __builtin_bit_cast(float, hs.x << 16);
        a[1] += ep * __builtin_bit_cast(float, hs.x & 0xffff0000u);
        a[2] += ep * __builtin_bit_cast(float, hs.y << 16);
        a[3] += ep * __builtin_bit_cast(float, hs.y & 0xffff0000u);
        a[4] += ep * __builtin_bit_cast(float, hs.z << 16);
        a[5] += ep * __builtin_bit_cast(float, hs.z & 0xffff0000u);
        a[6] += ep * __builtin_bit_cast(float, hs.w << 16);
        a[7] += ep * __builtin_bit_cast(float, hs.w & 0xffff0000u);
        uint4 o;
        o.x = (unsigned)f2b(a[0]) | ((unsigned)f2b(a[1]) << 16);
        o.y = (unsigned)f2b(a[2]) | ((unsigned)f2b(a[3]) << 16);
        o.z = (unsigned)f2b(a[4]) | ((unsigned)f2b(a[5]) << 16);
        o.w = (unsigned)f2b(a[6]) | ((unsigned)f2b(a[7]) << 16);
        *(uint4*)(pooled + (size_t)n*128 + u*8) = o;
    }
}

// ---------------- GIN MLP v3: wave-owns-tile, zero barriers, grid-stride ----------------
// Each wave processes a 16-row tile end-to-end: GEMM1 (A from global, W1 from L1/L2-hot
// global broadcast) -> BN/ReLU -> wave-private LDS Y -> GEMM2 -> BN/ReLU -> LDS -> packed
// write + fused graph pooling. No __syncthreads anywhere.
__global__ __launch_bounds__(256, 4) void k_gin(const unsigned short* __restrict__ Ain,
                                                unsigned short* __restrict__ Out,
                                                const unsigned short* __restrict__ W1t,
                                                const unsigned short* __restrict__ W2t,
                                                const float* __restrict__ b1, const float* __restrict__ g1,
                                                const float* __restrict__ bt1,
                                                const float* __restrict__ b2, const float* __restrict__ g2,
                                                const float* __restrict__ bt2,
                                                float* __restrict__ Gout){
    __shared__ __align__(16) unsigned short Ys[4][16*LDA];
    int t = threadIdx.x;
    int lane = t & 63, wv = t >> 6;
    int m = lane & 15, q = lane >> 4;
    unsigned short* Y = &Ys[wv][0];

    // fold BN: v = acc*ge + ce
    float ge1[8], ce1[8], ge2[8], ce2[8];
    #pragma unroll
    for (int j = 0; j < 8; ++j){
        int colc = j*16 + m;
        float gv = g1[colc];
        ge1[j] = gv; ce1[j] = b1[colc]*gv + bt1[colc];
        gv = g2[colc];
        ge2[j] = gv; ce2[j] = b2[colc]*gv + bt2[colc];
    }

    for (int tile = blockIdx.x; tile < NTILE64; tile += gridDim.x){
        int row0 = tile*64 + wv*16;
        int node = row0 + m;
        bool valid = node < NN;
        size_t nclamp = (size_t)(valid ? node : (NN-1));

        // ---- GEMM1: a-frags from global ----
        bf16x8 a[4];
        #pragma unroll
        for (int kk = 0; kk < 4; ++kk){
            int4 v = *(const int4*)(Ain + nclamp*128 + kk*32 + q*8);
            if (!valid) v = make_int4(0,0,0,0);
            a[kk] = __builtin_bit_cast(bf16x8, v);
        }
        f32x4 acc[8];
        #pragma unroll
        for (int j = 0; j < 8; ++j) acc[j] = (f32x4){0.f,0.f,0.f,0.f};
        #pragma unroll
        for (int kk = 0; kk < 4; ++kk){
            #pragma unroll
            for (int j = 0; j < 8; ++j){
                bf16x8 b = *(const bf16x8*)(W1t + (j*16 + m)*128 + kk*32 + q*8);
                acc[j] = __builtin_amdgcn_mfma_f32_16x16x32_bf16(a[kk], b, acc[j], 0, 0, 0);
            }
        }
        // epilogue 1 -> wave-private Y (no barrier; lgkm-ordered within wave)
        #pragma unroll
        for (int j = 0; j < 8; ++j){
            int colc = j*16 + m;
            #pragma unroll
            for (int r = 0; r < 4; ++r){
                float v = fmaxf(acc[j][r]*ge1[j] + ce1[j], 0.f);
                Y[(q*4 + r)*LDA + colc] = f2b(v);
            }
        }
        // ---- GEMM2: a-frags from own Y ----
        #pragma unroll
        for (int kk = 0; kk < 4; ++kk)
            a[kk] = *(const bf16x8*)(&Y[m*LDA + kk*32 + q*8]);
        #pragma unroll
        for (int j = 0; j < 8; ++j) acc[j] = (f32x4){0.f,0.f,0.f,0.f};
        #pragma unroll
        for (int kk = 0; kk < 4; ++kk){
            #pragma unroll
            for (int j = 0; j < 8; ++j){
                bf16x8 b = *(const bf16x8*)(W2t + (j*16 + m)*128 + kk*32 + q*8);
                acc[j] = __builtin_amdgcn_mfma_f32_16x16x32_bf16(a[kk], b, acc[j], 0, 0, 0);
            }
        }
        #pragma unroll
        for (int j = 0; j < 8; ++j){
            int colc = j*16 + m;
            #pragma unroll
            for (int r = 0; r < 4; ++r){
                float v = fmaxf(acc[j][r]*ge2[j] + ce2[j], 0.f);
                Y[(q*4 + r)*LDA + colc] = f2b(v);
            }
        }
        // ---- packed output write ----
        #pragma unroll
        for (int i = 0; i < 4; ++i){
            int idx = i*64 + lane;
            int r = idx >> 4, c = idx & 15;
            int nd = row0 + r;
            if (nd < NN)
                *(int4*)(Out + (size_t)nd*128 + c*8) = *(const int4*)(&Y[r*LDA + c*8]);
        }
        // ---- fused graph pooling: lane covers cols lane, lane+64 over 16 rows ----
        {
            float run0 = 0.f, run1 = 0.f;
            int curg = row0 / GSZ;
            for (int r = 0; r < 16; ++r){
                int nd = row0 + r;
                if (nd >= NN) break;
                int g = nd / GSZ;
                if (g != curg){
                    if (run0 != 0.f) atomicAdd(&Gout[curg*128 + lane], run0);
                    if (run1 != 0.f) atomicAdd(&Gout[curg*128 + lane + 64], run1);
                    run0 = 0.f; run1 = 0.f; curg = g;
                }
                run0 += b2f(Y[r*LDA + lane]);
                run1 += b2f(Y[r*LDA + lane + 64]);
            }
            if (run0 != 0.f) atomicAdd(&Gout[curg*128 + lane], run0);
            if (run1 != 0.f) atomicAdd(&Gout[curg*128 + lane + 64], run1);
        }
    }
}

// ---------------- score heads ----------------
__global__ __launch_bounds__(256) void k_score(const float* __restrict__ G,
                                               const float* __restrict__ W0, const float* __restrict__ b0,
                                               const float* __restrict__ Wk, const float* __restrict__ bk,
                                               float* __restrict__ out){
    int id = blockIdx.x*256 + threadIdx.x;
    if (id >= BB*OUTC) return;
    int b = id / OUTC, o = id % OUTC;
    float s = b0[o];
    #pragma unroll
    for (int k = 0; k < 4; ++k) s += bk[k*OUTC + o];
    const float* g0 = G + b*128;
    for (int c = 0; c < 128; ++c) s += g0[c] * W0[c*OUTC + o];
    for (int k = 0; k < 4; ++k){
        const float* gk = G + (size_t)(k+1)*BB*128 + b*128;
        const float* wk = Wk + k*128*OUTC;
        for (int c = 0; c < 128; ++c) s += gk[c] * wk[c*OUTC + o];
    }
    out[id] = s;
}

extern "C" void kernel_launch(void* const* d_in, const int* in_sizes, int n_in,
                              void* d_out, int out_size, void* d_ws, size_t ws_size,
                              hipStream_t stream){
    const float* node_features = (const float*)d_in[0];
    const int*   edge_src  = (const int*)d_in[1];
    const int*   edge_dst  = (const int*)d_in[2];
    const float* eps       = (const float*)d_in[4];
    const float* pre_W1    = (const float*)d_in[5];
    const float* pre_b1    = (const float*)d_in[6];
    const float* pre_g1    = (const float*)d_in[7];
    const float* pre_bt1   = (const float*)d_in[8];
    const float* pre_W2    = (const float*)d_in[9];
    const float* pre_b2    = (const float*)d_in[10];
    const float* pre_gout  = (const float*)d_in[11];
    const float* pre_btout = (const float*)d_in[12];
    const float* mlp_W1    = (const float*)d_in[13];
    const float* mlp_b1    = (const float*)d_in[14];
    const float* mlp_g1    = (const float*)d_in[15];
    const float* mlp_bt1   = (const float*)d_in[16];
    const float* mlp_W2    = (const float*)d_in[17];
    const float* mlp_b2    = (const float*)d_in[18];
    const float* bn_g      = (const float*)d_in[19];
    const float* bn_bt     = (const float*)d_in[20];
    const float* pred_W0   = (const float*)d_in[21];
    const float* pred_b0   = (const float*)d_in[22];
    const float* pred_W    = (const float*)d_in[23];
    const float* pred_b    = (const float*)d_in[24];
    float* out = (float*)d_out;

    char* p = (char*)d_ws;
    auto alloc = [&](size_t bytes)->char*{
        char* r = p;
        p += (bytes + 255) & ~(size_t)255;
        return r;
    };
    int* bucket_cursor    = (int*)alloc((size_t)NBKT*4);
    int* bucket_base      = (int*)alloc((size_t)(NBKT+1)*4);
    int* row_ptr          = (int*)alloc((size_t)(NN+1)*4);
    int* col              = (int*)alloc((size_t)EE*4);
    unsigned int* ebuf    = (unsigned int*)alloc((size_t)NBKT*BCAP*4);
    unsigned short* Wbf   = (unsigned short*)alloc((size_t)8*128*128*2);
    unsigned short* hA    = (unsigned short*)alloc((size_t)NN*128*2);
    unsigned short* hB    = (unsigned short*)alloc((size_t)NN*128*2);
    unsigned short* pooled= (unsigned short*)alloc((size_t)NN*128*2);
    float* G              = (float*)alloc((size_t)5*BB*128*4);

    hipMemsetAsync(bucket_cursor, 0, (size_t)NBKT*4, stream);

    k_bucket<<<(EE + EPB - 1)/EPB, 256, 0, stream>>>(edge_src, edge_dst, bucket_cursor, ebuf);
    k_bscan<<<1, 1024, 0, stream>>>(bucket_cursor, bucket_base, row_ptr);
    k_csr<<<NBKT, 256, 0, stream>>>(bucket_cursor, bucket_base, ebuf, row_ptr, col);

    k_input<<<BB, 256, 0, stream>>>(node_features, hA, G);
    k_prep<<<512, 256, 0, stream>>>(pre_W1, pre_W2, mlp_W1, mlp_W2, Wbf);

    const unsigned short* hcur = hA;
    unsigned short* hnxt = hB;
    for (int l = 0; l < 4; ++l){
        k_agg<<<NN/4, 256, 0, stream>>>(row_ptr, col, hcur, eps, l, pooled);
        const unsigned short *W1t, *W2t;
        const float *b1,*g1,*bt1,*b2,*g2,*bt2;
        if (l == 0){
            W1t = Wbf;             W2t = Wbf + 16384;
            b1 = pre_b1; g1 = pre_g1; bt1 = pre_bt1;
            b2 = pre_b2; g2 = pre_gout; bt2 = pre_btout;
        } else {
            W1t = Wbf + (size_t)(2 + (l-1))*16384;
            W2t = Wbf + (size_t)(5 + (l-1))*16384;
            b1 = mlp_b1 + (l-1)*128; g1 = mlp_g1 + (l-1)*128; bt1 = mlp_bt1 + (l-1)*128;
            b2 = mlp_b2 + (l-1)*128; g2 = bn_g   + (l-1)*128; bt2 = bn_bt   + (l-1)*128;
        }
        k_gin<<<1024, 256, 0, stream>>>(pooled, hnxt, W1t, W2t, b1,g1,bt1, b2,g2,bt2,
                                        G + (size_t)(l+1)*BB*128);
        const unsigned short* tmp = hnxt;
        hnxt = (unsigned short*)hcur;
        hcur = tmp;
    }
    k_score<<<(BB*OUTC + 255)/256, 256, 0, stream>>>(G, pred_W0, pred_b0, pred_W, pred_b, out);
}

// Round 7
// 636.339 us; speedup vs baseline: 1.7965x; 1.7965x over previous
//
#include <hip/hip_runtime.h>
#include <hip/hip_bf16.h>

#define NN 100000
#define EE 1600000
#define HH 128
#define OUTC 10
#define BB 500
#define GSZ 200
#define LDA 136   // 128 + 8 bf16 pad (for Y transpose tiles)

#define NBKT 782          // ceil(NN/128)
#define BCAP 2560
#define EPB 4096
#define NTILE64 1563      // ceil(NN/64)

typedef float f32x4 __attribute__((ext_vector_type(4)));
typedef __bf16 bf16x8 __attribute__((ext_vector_type(8)));

__device__ __forceinline__ float b2f(unsigned short u){
    unsigned int x = ((unsigned int)u) << 16;
    return __builtin_bit_cast(float, x);
}
__device__ __forceinline__ unsigned short f2b(float f){
    __hip_bfloat16 h = __float2bfloat16(f);
    return __builtin_bit_cast(unsigned short, h);
}

// ---------------- CSR build: bucketed counting sort ----------------
__global__ __launch_bounds__(256) void k_bucket(const int* __restrict__ src, const int* __restrict__ dst,
                                                int* __restrict__ bucket_cursor, unsigned int* __restrict__ ebuf){
    __shared__ unsigned int val[EPB];
    __shared__ unsigned short bkt[EPB];
    __shared__ int hist[NBKT];
    int t = threadIdx.x;
    int e0 = blockIdx.x * EPB;
    for (int i = t; i < NBKT; i += 256) hist[i] = 0;
    __syncthreads();
    for (int i = t; i < EPB; i += 256){
        int e = e0 + i;
        if (e < EE){
            int d = dst[e];
            int b = d >> 7;
            val[i] = ((unsigned)src[e] << 7) | (unsigned)(d & 127);
            bkt[i] = (unsigned short)b;
            atomicAdd(&hist[b], 1);
        } else {
            bkt[i] = 0xffff;
        }
    }
    __syncthreads();
    for (int i = t; i < NBKT; i += 256){
        int c = hist[i];
        hist[i] = c ? atomicAdd(&bucket_cursor[i], c) : 0;
    }
    __syncthreads();
    for (int i = t; i < EPB; i += 256){
        unsigned short b = bkt[i];
        if (b != 0xffff){
            int pos = atomicAdd(&hist[b], 1);
            if (pos < BCAP) ebuf[(int)b * BCAP + pos] = val[i];
        }
    }
}

__global__ __launch_bounds__(1024) void k_bscan(const int* __restrict__ bucket_cursor,
                                                int* __restrict__ bucket_base, int* __restrict__ row_ptr){
    __shared__ int tmp[1024];
    int t = threadIdx.x;
    int v = (t < NBKT) ? min(bucket_cursor[t], BCAP) : 0;
    tmp[t] = v; __syncthreads();
    for (int off = 1; off < 1024; off <<= 1){
        int a = (t >= off) ? tmp[t - off] : 0;
        __syncthreads();
        tmp[t] += a;
        __syncthreads();
    }
    if (t < NBKT) bucket_base[t + 1] = tmp[t];
    if (t == 0){ bucket_base[0] = 0; row_ptr[NN] = EE; }
}

__global__ __launch_bounds__(256) void k_csr(const int* __restrict__ bucket_cursor, const int* __restrict__ bucket_base,
                                             const unsigned int* __restrict__ ebuf,
                                             int* __restrict__ row_ptr, int* __restrict__ col){
    __shared__ int cnt[128];
    __shared__ int pfx[128];
    int b = blockIdx.x;
    int t = threadIdx.x;
    int c    = min(bucket_cursor[b], BCAP);
    int base = bucket_base[b];
    if (t < 128) cnt[t] = 0;
    __syncthreads();
    const unsigned int* eb = ebuf + (size_t)b * BCAP;
    for (int i = t; i < c; i += 256) atomicAdd(&cnt[eb[i] & 127], 1);
    __syncthreads();
    if (t == 0){
        int run = 0;
        for (int i = 0; i < 128; ++i){ pfx[i] = run; run += cnt[i]; }
    }
    __syncthreads();
    int node0 = b * 128;
    if (t < 128 && node0 + t < NN) row_ptr[node0 + t] = base + pfx[t];
    if (t < 128) cnt[t] = pfx[t];
    __syncthreads();
    for (int i = t; i < c; i += 256){
        unsigned int v = eb[i];
        int pos = atomicAdd(&cnt[v & 127], 1);
        col[base + pos] = (int)(v >> 7);
    }
}

// ---------------- weight prep: fragment-contiguous layout ----------------
// chunk ((j*4+kk)*4+q)*16+m holds 8 shorts: W[n=j*16+m][k=kk*32+q*8+e]
__global__ __launch_bounds__(256) void k_prep(const float* __restrict__ preW1, const float* __restrict__ preW2,
                                              const float* __restrict__ mlpW1, const float* __restrict__ mlpW2,
                                              unsigned short* __restrict__ Wbf){
    int idx = blockIdx.x*256 + threadIdx.x;   // 8*16384
    int w = idx >> 14;
    int rem = idx & 16383;
    int e = rem & 7;
    int chunk = rem >> 3;
    int m = chunk & 15;
    int q = (chunk >> 4) & 3;
    int kk = (chunk >> 6) & 3;
    int j = chunk >> 8;
    int n = j*16 + m;
    int k = kk*32 + q*8 + e;
    const float* src;
    if      (w == 0) src = preW1;
    else if (w == 1) src = preW2;
    else if (w <  5) src = mlpW1 + (w-2)*16384;
    else             src = mlpW2 + (w-5)*16384;
    Wbf[idx] = f2b(src[k*128 + n]);
}

// ---------------- input: cast fp32->bf16 + pool reps[0] + zero G[1..4] ----------------
__global__ __launch_bounds__(256) void k_input(const float* __restrict__ x, unsigned short* __restrict__ hA,
                                               float* __restrict__ G){
    __shared__ float r0[256], r1[256];
    int t = threadIdx.x;
    int f2 = t & 63;
    int rg = t >> 6;
    int g  = blockIdx.x;
    if (t < 128){
        #pragma unroll
        for (int k = 1; k < 5; ++k) G[(size_t)k*BB*128 + g*128 + t] = 0.f;
    }
    float a0 = 0.f, a1 = 0.f;
    for (int i = rg; i < GSZ; i += 4){
        int node = g*GSZ + i;
        float2 v = *(const float2*)(x + (size_t)node*128 + f2*2);
        a0 += v.x; a1 += v.y;
        unsigned int o = (unsigned)f2b(v.x) | ((unsigned)f2b(v.y) << 16);
        ((unsigned int*)hA)[(size_t)node*64 + f2] = o;
    }
    r0[t] = a0; r1[t] = a1;
    __syncthreads();
    if (t < 64){
        float s0 = r0[t] + r0[t+64] + r0[t+128] + r0[t+192];
        float s1 = r1[t] + r1[t+64] + r1[t+128] + r1[t+192];
        float2 v; v.x = s0; v.y = s1;
        *(float2*)(G + g*128 + t*2) = v;
    }
}

// ---------------- aggregation (round-3 proven version) ----------------
__device__ __forceinline__ void acc_u32(float* a, unsigned int v, int j){
    a[j]   += __builtin_bit_cast(float, v << 16);
    a[j+1] += __builtin_bit_cast(float, v & 0xffff0000u);
}
__device__ __forceinline__ void acc_u4(float* a, uint4 v){
    acc_u32(a, v.x, 0); acc_u32(a, v.y, 2); acc_u32(a, v.z, 4); acc_u32(a, v.w, 6);
}

__global__ __launch_bounds__(256) void k_agg(const int* __restrict__ row_ptr, const int* __restrict__ col,
                                             const unsigned short* __restrict__ h,
                                             const float* __restrict__ eps, int l,
                                             unsigned short* __restrict__ pooled){
    int lane = threadIdx.x & 63;
    int wv   = threadIdx.x >> 6;
    int n    = blockIdx.x*4 + wv;
    int q = lane >> 4;
    int u = lane & 15;
    int beg = row_ptr[n], end = row_ptr[n+1];
    float a[8];
    #pragma unroll
    for (int j = 0; j < 8; ++j) a[j] = 0.f;

    int e = beg;
    for (; e + 16 <= end; e += 16){
        int c0 = col[e      + q];
        int c1 = col[e + 4  + q];
        int c2 = col[e + 8  + q];
        int c3 = col[e + 12 + q];
        uint4 v0 = *(const uint4*)(h + (size_t)c0*128 + u*8);
        uint4 v1 = *(const uint4*)(h + (size_t)c1*128 + u*8);
        uint4 v2 = *(const uint4*)(h + (size_t)c2*128 + u*8);
        uint4 v3 = *(const uint4*)(h + (size_t)c3*128 + u*8);
        acc_u4(a, v0); acc_u4(a, v1); acc_u4(a, v2); acc_u4(a, v3);
    }
    for (; e + 4 <= end; e += 4){
        int c = col[e + q];
        uint4 v = *(const uint4*)(h + (size_t)c*128 + u*8);
        acc_u4(a, v);
    }
    if (e < end){
        if (e + q < end){
            int c = col[e + q];
            uint4 v = *(const uint4*)(h + (size_t)c*128 + u*8);
            acc_u4(a, v);
        }
    }
    #pragma unroll
    for (int j = 0; j < 8; ++j){
        a[j] += __shfl_xor(a[j], 16, 64);
        a[j] += __shfl_xor(a[j], 32, 64);
    }
    if (q == 0){
        float ep = 1.0f + eps[l];
        uint4 hs = *(const uint4*)(h + (size_t)n*128 + u*8);
        a[0] += ep * __builtin_bit_cast(float, hs.x << 16);
        a[1] += ep * __builtin_bit_cast(float, hs.x & 0xffff0000u);
        a[2] += ep * __builtin_bit_cast(float, hs.y << 16);
        a[3] += ep * __builtin_bit_cast(float, hs.y & 0xffff0000u);
        a[4] += ep * __builtin_bit_cast(float, hs.z << 16);
        a[5] += ep * __builtin_bit_cast(float, hs.z & 0xffff0000u);
        a[6] += ep * __builtin_bit_cast(float, hs.w << 16);
        a[7] += ep * __builtin_bit_cast(float, hs.w & 0xffff0000u);
        uint4 o;
        o.x = (unsigned)f2b(a[0]) | ((unsigned)f2b(a[1]) << 16);
        o.y = (unsigned)f2b(a[2]) | ((unsigned)f2b(a[3]) << 16);
        o.z = (unsigned)f2b(a[4]) | ((unsigned)f2b(a[5]) << 16);
        o.w = (unsigned)f2b(a[6]) | ((unsigned)f2b(a[7]) << 16);
        *(uint4*)(pooled + (size_t)n*128 + u*8) = o;
    }
}

// ---------------- MLP stage 1: Y = relu(g*(A@W+b)+bt), in-place on pooled ----------------
// Persistent blocks; W in LDS (frag-contiguous, staged once); wave-private Y transpose tile;
// no __syncthreads in the tile loop.
__global__ __launch_bounds__(256, 4) void k_mlp1(const unsigned short* __restrict__ Ain,
                                                 unsigned short* __restrict__ Yout,
                                                 const unsigned short* __restrict__ Wf,
                                                 const float* __restrict__ bb, const float* __restrict__ gg,
                                                 const float* __restrict__ bt){
    __shared__ __align__(16) unsigned short Wl[16384];
    __shared__ __align__(16) unsigned short Ys[4][16*LDA];
    int t = threadIdx.x;
    int lane = t & 63, wv = t >> 6;
    int m = lane & 15, q = lane >> 4;
    for (int i = t; i < 2048; i += 256)
        *(int4*)(&Wl[i*8]) = *(const int4*)(Wf + i*8);
    __syncthreads();
    float ge[8], ce[8];
    #pragma unroll
    for (int j = 0; j < 8; ++j){
        int colc = j*16 + m;
        float gv = gg[colc];
        ge[j] = gv; ce[j] = bb[colc]*gv + bt[colc];
    }
    unsigned short* Y = &Ys[wv][0];
    for (int tile = blockIdx.x; tile < NTILE64; tile += gridDim.x){
        int row0 = tile*64 + wv*16;
        int node = row0 + m;
        bool valid = node < NN;
        size_t nb = (size_t)(valid ? node : 0) * 128;
        bf16x8 a[4];
        #pragma unroll
        for (int kk = 0; kk < 4; ++kk){
            int4 v = *(const int4*)(Ain + nb + kk*32 + q*8);
            if (!valid) v = make_int4(0,0,0,0);
            a[kk] = __builtin_bit_cast(bf16x8, v);
        }
        f32x4 acc[8];
        #pragma unroll
        for (int j = 0; j < 8; ++j) acc[j] = (f32x4){0.f,0.f,0.f,0.f};
        #pragma unroll
        for (int kk = 0; kk < 4; ++kk){
            #pragma unroll
            for (int j = 0; j < 8; ++j){
                bf16x8 b = *(const bf16x8*)(&Wl[((((j*4+kk)*4+q)*16)+m)*8]);
                acc[j] = __builtin_amdgcn_mfma_f32_16x16x32_bf16(a[kk], b, acc[j], 0, 0, 0);
            }
        }
        #pragma unroll
        for (int j = 0; j < 8; ++j){
            int colc = j*16 + m;
            #pragma unroll
            for (int r = 0; r < 4; ++r){
                float v = fmaxf(acc[j][r]*ge[j] + ce[j], 0.f);
                Y[(q*4 + r)*LDA + colc] = f2b(v);
            }
        }
        #pragma unroll
        for (int i = 0; i < 4; ++i){
            int idx = i*64 + lane;
            int r = idx >> 4, c = idx & 15;
            int nd = tile*64 + wv*16 + r;
            if (nd < NN)
                *(int4*)(Yout + (size_t)nd*128 + c*8) = *(const int4*)(&Y[r*LDA + c*8]);
        }
    }
}

// ---------------- MLP stage 2: Out = relu(g*(Y@W+b)+bt) + fused graph pooling ----------------
__global__ __launch_bounds__(256, 4) void k_mlp2(const unsigned short* __restrict__ Ain,
                                                 unsigned short* __restrict__ Out,
                                                 const unsigned short* __restrict__ Wf,
                                                 const float* __restrict__ bb, const float* __restrict__ gg,
                                                 const float* __restrict__ bt,
                                                 float* __restrict__ Gout){
    __shared__ __align__(16) unsigned short Wl[16384];
    __shared__ __align__(16) unsigned short Ys[4][16*LDA];
    int t = threadIdx.x;
    int lane = t & 63, wv = t >> 6;
    int m = lane & 15, q = lane >> 4;
    for (int i = t; i < 2048; i += 256)
        *(int4*)(&Wl[i*8]) = *(const int4*)(Wf + i*8);
    __syncthreads();
    float ge[8], ce[8];
    #pragma unroll
    for (int j = 0; j < 8; ++j){
        int colc = j*16 + m;
        float gv = gg[colc];
        ge[j] = gv; ce[j] = bb[colc]*gv + bt[colc];
    }
    unsigned short* Y = &Ys[wv][0];
    for (int tile = blockIdx.x; tile < NTILE64; tile += gridDim.x){
        int row0 = tile*64 + wv*16;
        int node = row0 + m;
        bool valid = node < NN;
        size_t nb = (size_t)(valid ? node : 0) * 128;
        bf16x8 a[4];
        #pragma unroll
        for (int kk = 0; kk < 4; ++kk){
            int4 v = *(const int4*)(Ain + nb + kk*32 + q*8);
            if (!valid) v = make_int4(0,0,0,0);
            a[kk] = __builtin_bit_cast(bf16x8, v);
        }
        f32x4 acc[8];
        #pragma unroll
        for (int j = 0; j < 8; ++j) acc[j] = (f32x4){0.f,0.f,0.f,0.f};
        #pragma unroll
        for (int kk = 0; kk < 4; ++kk){
            #pragma unroll
            for (int j = 0; j < 8; ++j){
                bf16x8 b = *(const bf16x8*)(&Wl[((((j*4+kk)*4+q)*16)+m)*8]);
                acc[j] = __builtin_amdgcn_mfma_f32_16x16x32_bf16(a[kk], b, acc[j], 0, 0, 0);
            }
        }
        #pragma unroll
        for (int j = 0; j < 8; ++j){
            int colc = j*16 + m;
            #pragma unroll
            for (int r = 0; r < 4; ++r){
                float v = fmaxf(acc[j][r]*ge[j] + ce[j], 0.f);
                Y[(q*4 + r)*LDA + colc] = f2b(v);
            }
        }
        #pragma unroll
        for (int i = 0; i < 4; ++i){
            int idx = i*64 + lane;
            int r = idx >> 4, c = idx & 15;
            int nd = tile*64 + wv*16 + r;
            if (nd < NN)
                *(int4*)(Out + (size_t)nd*128 + c*8) = *(const int4*)(&Y[r*LDA + c*8]);
        }
        // fused graph pooling: lane covers feature cols lane, lane+64 over this wave's 16 rows
        {
            float run0 = 0.f, run1 = 0.f;
            int curg = row0 / GSZ;
            for (int r = 0; r < 16; ++r){
                int nd = row0 + r;
                if (nd >= NN) break;
                int g = nd / GSZ;
                if (g != curg){
                    if (run0 != 0.f) atomicAdd(&Gout[curg*128 + lane], run0);
                    if (run1 != 0.f) atomicAdd(&Gout[curg*128 + lane + 64], run1);
                    run0 = 0.f; run1 = 0.f; curg = g;
                }
                run0 += b2f(Y[r*LDA + lane]);
                run1 += b2f(Y[r*LDA + lane + 64]);
            }
            if (run0 != 0.f) atomicAdd(&Gout[curg*128 + lane], run0);
            if (run1 != 0.f) atomicAdd(&Gout[curg*128 + lane + 64], run1);
        }
    }
}

// ---------------- score heads ----------------
__global__ __launch_bounds__(256) void k_score(const float* __restrict__ G,
                                               const float* __restrict__ W0, const float* __restrict__ b0,
                                               const float* __restrict__ Wk, const float* __restrict__ bk,
                                               float* __restrict__ out){
    int id = blockIdx.x*256 + threadIdx.x;
    if (id >= BB*OUTC) return;
    int b = id / OUTC, o = id % OUTC;
    float s = b0[o];
    #pragma unroll
    for (int k = 0; k < 4; ++k) s += bk[k*OUTC + o];
    const float* g0 = G + b*128;
    for (int c = 0; c < 128; ++c) s += g0[c] * W0[c*OUTC + o];
    for (int k = 0; k < 4; ++k){
        const float* gk = G + (size_t)(k+1)*BB*128 + b*128;
        const float* wk = Wk + k*128*OUTC;
        for (int c = 0; c < 128; ++c) s += gk[c] * wk[c*OUTC + o];
    }
    out[id] = s;
}

extern "C" void kernel_launch(void* const* d_in, const int* in_sizes, int n_in,
                              void* d_out, int out_size, void* d_ws, size_t ws_size,
                              hipStream_t stream){
    const float* node_features = (const float*)d_in[0];
    const int*   edge_src  = (const int*)d_in[1];
    const int*   edge_dst  = (const int*)d_in[2];
    const float* eps       = (const float*)d_in[4];
    const float* pre_W1    = (const float*)d_in[5];
    const float* pre_b1    = (const float*)d_in[6];
    const float* pre_g1    = (const float*)d_in[7];
    const float* pre_bt1   = (const float*)d_in[8];
    const float* pre_W2    = (const float*)d_in[9];
    const float* pre_b2    = (const float*)d_in[10];
    const float* pre_gout  = (const float*)d_in[11];
    const float* pre_btout = (const float*)d_in[12];
    const float* mlp_W1    = (const float*)d_in[13];
    const float* mlp_b1    = (const float*)d_in[14];
    const float* mlp_g1    = (const float*)d_in[15];
    const float* mlp_bt1   = (const float*)d_in[16];
    const float* mlp_W2    = (const float*)d_in[17];
    const float* mlp_b2    = (const float*)d_in[18];
    const float* bn_g      = (const float*)d_in[19];
    const float* bn_bt     = (const float*)d_in[20];
    const float* pred_W0   = (const float*)d_in[21];
    const float* pred_b0   = (const float*)d_in[22];
    const float* pred_W    = (const float*)d_in[23];
    const float* pred_b    = (const float*)d_in[24];
    float* out = (float*)d_out;

    char* p = (char*)d_ws;
    auto alloc = [&](size_t bytes)->char*{
        char* r = p;
        p += (bytes + 255) & ~(size_t)255;
        return r;
    };
    int* bucket_cursor    = (int*)alloc((size_t)NBKT*4);
    int* bucket_base      = (int*)alloc((size_t)(NBKT+1)*4);
    int* row_ptr          = (int*)alloc((size_t)(NN+1)*4);
    int* col              = (int*)alloc((size_t)EE*4);
    unsigned int* ebuf    = (unsigned int*)alloc((size_t)NBKT*BCAP*4);
    unsigned short* Wbf   = (unsigned short*)alloc((size_t)8*128*128*2);
    unsigned short* hA    = (unsigned short*)alloc((size_t)NN*128*2);
    unsigned short* hB    = (unsigned short*)alloc((size_t)NN*128*2);
    unsigned short* pooled= (unsigned short*)alloc((size_t)NN*128*2);
    float* G              = (float*)alloc((size_t)5*BB*128*4);

    hipMemsetAsync(bucket_cursor, 0, (size_t)NBKT*4, stream);

    k_bucket<<<(EE + EPB - 1)/EPB, 256, 0, stream>>>(edge_src, edge_dst, bucket_cursor, ebuf);
    k_bscan<<<1, 1024, 0, stream>>>(bucket_cursor, bucket_base, row_ptr);
    k_csr<<<NBKT, 256, 0, stream>>>(bucket_cursor, bucket_base, ebuf, row_ptr, col);

    k_input<<<BB, 256, 0, stream>>>(node_features, hA, G);
    k_prep<<<512, 256, 0, stream>>>(pre_W1, pre_W2, mlp_W1, mlp_W2, Wbf);

    const unsigned short* hcur = hA;
    unsigned short* hnxt = hB;
    for (int l = 0; l < 4; ++l){
        k_agg<<<NN/4, 256, 0, stream>>>(row_ptr, col, hcur, eps, l, pooled);
        const unsigned short *W1t, *W2t;
        const float *b1,*g1,*bt1,*b2,*g2,*bt2;
        if (l == 0){
            W1t = Wbf;             W2t = Wbf + 16384;
            b1 = pre_b1; g1 = pre_g1; bt1 = pre_bt1;
            b2 = pre_b2; g2 = pre_gout; bt2 = pre_btout;
        } else {
            W1t = Wbf + (size_t)(2 + (l-1))*16384;
            W2t = Wbf + (size_t)(5 + (l-1))*16384;
            b1 = mlp_b1 + (l-1)*128; g1 = mlp_g1 + (l-1)*128; bt1 = mlp_bt1 + (l-1)*128;
            b2 = mlp_b2 + (l-1)*128; g2 = bn_g   + (l-1)*128; bt2 = bn_bt   + (l-1)*128;
        }
        k_mlp1<<<768, 256, 0, stream>>>(pooled, pooled, W1t, b1, g1, bt1);
        k_mlp2<<<768, 256, 0, stream>>>(pooled, hnxt, W2t, b2, g2, bt2,
                                        G + (size_t)(l+1)*BB*128);
        const unsigned short* tmp = hnxt;
        hnxt = (unsigned short*)hcur;
        hcur = tmp;
    }
    k_score<<<(BB*OUTC + 255)/256, 256, 0, stream>>>(G, pred_W0, pred_b0, pred_W, pred_b, out);
}

// Round 8
// 606.497 us; speedup vs baseline: 1.8849x; 1.0492x over previous
//
#include <hip/hip_runtime.h>
#include <hip/hip_bf16.h>

#define NN 100000
#define EE 1600000
#define HH 128
#define OUTC 10
#define BB 500
#define GSZ 200
#define LDA 136   // 128 + 8 bf16 pad (Y transpose tiles)

#define NBKT 782          // ceil(NN/128)
#define BCAP 2560
#define EPB 4096
#define NBUCKB 391        // ceil(EE/EPB)
#define NTILE64 1563      // ceil(NN/64)

typedef float f32x4 __attribute__((ext_vector_type(4)));
typedef __bf16 bf16x8 __attribute__((ext_vector_type(8)));

__device__ __forceinline__ float b2f(unsigned short u){
    unsigned int x = ((unsigned int)u) << 16;
    return __builtin_bit_cast(float, x);
}
__device__ __forceinline__ unsigned short f2b(float f){
    __hip_bfloat16 h = __float2bfloat16(f);
    return __builtin_bit_cast(unsigned short, h);
}

// ---------------- fused setup: edge bucketing + input cast/pool + weight prep ----------------
__global__ __launch_bounds__(256) void k_setup(const int* __restrict__ src, const int* __restrict__ dst,
                                               int* __restrict__ bucket_cursor, unsigned int* __restrict__ ebuf,
                                               const float* __restrict__ x, unsigned short* __restrict__ hA,
                                               float* __restrict__ G,
                                               const float* __restrict__ preW1, const float* __restrict__ preW2,
                                               const float* __restrict__ mlpW1, const float* __restrict__ mlpW2,
                                               unsigned short* __restrict__ Wbf){
    __shared__ __align__(16) unsigned int sval[EPB];     // 16 KB (input path reuses as r0/r1)
    __shared__ unsigned short sbkt[EPB];                 // 8 KB
    __shared__ int shist[NBKT];                          // 3.1 KB
    int t = threadIdx.x;
    int bid = blockIdx.x;

    if (bid < NBUCKB){
        // ---- edge bucketing ----
        int e0 = bid * EPB;
        for (int i = t; i < NBKT; i += 256) shist[i] = 0;
        __syncthreads();
        for (int i = t; i < EPB; i += 256){
            int e = e0 + i;
            if (e < EE){
                int d = dst[e];
                int b = d >> 7;
                sval[i] = ((unsigned)src[e] << 7) | (unsigned)(d & 127);
                sbkt[i] = (unsigned short)b;
                atomicAdd(&shist[b], 1);
            } else {
                sbkt[i] = 0xffff;
            }
        }
        __syncthreads();
        for (int i = t; i < NBKT; i += 256){
            int c = shist[i];
            shist[i] = c ? atomicAdd(&bucket_cursor[i], c) : 0;
        }
        __syncthreads();
        for (int i = t; i < EPB; i += 256){
            unsigned short b = sbkt[i];
            if (b != 0xffff){
                int pos = atomicAdd(&shist[b], 1);
                if (pos < BCAP) ebuf[(int)b * BCAP + pos] = sval[i];
            }
        }
    } else if (bid < NBUCKB + BB){
        // ---- input: cast fp32->bf16 + pool reps[0] + zero G[1..4] ----
        float* r0 = (float*)sval;
        float* r1 = r0 + 256;
        int g = bid - NBUCKB;
        int f2 = t & 63;
        int rg = t >> 6;
        if (t < 128){
            #pragma unroll
            for (int k = 1; k < 5; ++k) G[(size_t)k*BB*128 + g*128 + t] = 0.f;
        }
        float a0 = 0.f, a1 = 0.f;
        for (int i = rg; i < GSZ; i += 4){
            int node = g*GSZ + i;
            float2 v = *(const float2*)(x + (size_t)node*128 + f2*2);
            a0 += v.x; a1 += v.y;
            unsigned int o = (unsigned)f2b(v.x) | ((unsigned)f2b(v.y) << 16);
            ((unsigned int*)hA)[(size_t)node*64 + f2] = o;
        }
        r0[t] = a0; r1[t] = a1;
        __syncthreads();
        if (t < 64){
            float s0 = r0[t] + r0[t+64] + r0[t+128] + r0[t+192];
            float s1 = r1[t] + r1[t+64] + r1[t+128] + r1[t+192];
            float2 v; v.x = s0; v.y = s1;
            *(float2*)(G + g*128 + t*2) = v;
        }
    } else {
        // ---- weight prep: fragment-contiguous bf16 ----
        int idx = (bid - NBUCKB - BB)*256 + t;   // 8*16384
        int w = idx >> 14;
        int rem = idx & 16383;
        int e = rem & 7;
        int chunk = rem >> 3;
        int m = chunk & 15;
        int q = (chunk >> 4) & 3;
        int kk = (chunk >> 6) & 3;
        int j = chunk >> 8;
        int n = j*16 + m;
        int k = kk*32 + q*8 + e;
        const float* s;
        if      (w == 0) s = preW1;
        else if (w == 1) s = preW2;
        else if (w <  5) s = mlpW1 + (w-2)*16384;
        else             s = mlpW2 + (w-5)*16384;
        Wbf[idx] = f2b(s[k*128 + n]);
    }
}

__global__ __launch_bounds__(1024) void k_bscan(const int* __restrict__ bucket_cursor,
                                                int* __restrict__ bucket_base, int* __restrict__ row_ptr){
    __shared__ int tmp[1024];
    int t = threadIdx.x;
    int v = (t < NBKT) ? min(bucket_cursor[t], BCAP) : 0;
    tmp[t] = v; __syncthreads();
    for (int off = 1; off < 1024; off <<= 1){
        int a = (t >= off) ? tmp[t - off] : 0;
        __syncthreads();
        tmp[t] += a;
        __syncthreads();
    }
    if (t < NBKT) bucket_base[t + 1] = tmp[t];
    if (t == 0){ bucket_base[0] = 0; row_ptr[NN] = EE; }
}

__global__ __launch_bounds__(256) void k_csr(const int* __restrict__ bucket_cursor, const int* __restrict__ bucket_base,
                                             const unsigned int* __restrict__ ebuf,
                                             int* __restrict__ row_ptr, int* __restrict__ col){
    __shared__ int cnt[128];
    __shared__ int pfx[128];
    int b = blockIdx.x;
    int t = threadIdx.x;
    int c    = min(bucket_cursor[b], BCAP);
    int base = bucket_base[b];
    if (t < 128) cnt[t] = 0;
    __syncthreads();
    const unsigned int* eb = ebuf + (size_t)b * BCAP;
    for (int i = t; i < c; i += 256) atomicAdd(&cnt[eb[i] & 127], 1);
    __syncthreads();
    if (t == 0){
        int run = 0;
        for (int i = 0; i < 128; ++i){ pfx[i] = run; run += cnt[i]; }
    }
    __syncthreads();
    int node0 = b * 128;
    if (t < 128 && node0 + t < NN) row_ptr[node0 + t] = base + pfx[t];
    if (t < 128) cnt[t] = pfx[t];
    __syncthreads();
    for (int i = t; i < c; i += 256){
        unsigned int v = eb[i];
        int pos = atomicAdd(&cnt[v & 127], 1);
        col[base + pos] = (int)(v >> 7);
    }
}

// ---------------- aggregation with masked-tail ILP ----------------
__device__ __forceinline__ void acc_u32(float* a, unsigned int v, int j){
    a[j]   += __builtin_bit_cast(float, v << 16);
    a[j+1] += __builtin_bit_cast(float, v & 0xffff0000u);
}
__device__ __forceinline__ void acc_u4(float* a, uint4 v){
    acc_u32(a, v.x, 0); acc_u32(a, v.y, 2); acc_u32(a, v.z, 4); acc_u32(a, v.w, 6);
}
__device__ __forceinline__ uint4 and4(uint4 v, unsigned mk){
    v.x &= mk; v.y &= mk; v.z &= mk; v.w &= mk; return v;
}

__global__ __launch_bounds__(256) void k_agg(const int* __restrict__ row_ptr, const int* __restrict__ col,
                                             const unsigned short* __restrict__ h,
                                             const float* __restrict__ eps, int l,
                                             unsigned short* __restrict__ pooled){
    int lane = threadIdx.x & 63;
    int wv   = threadIdx.x >> 6;
    int n    = blockIdx.x*4 + wv;
    int q = lane >> 4;
    int u = lane & 15;
    int beg = row_ptr[n], end = row_ptr[n+1];
    float a[8];
    #pragma unroll
    for (int j = 0; j < 8; ++j) a[j] = 0.f;

    int e = beg;
    for (; e + 16 <= end; e += 16){
        int c0 = col[e      + q];
        int c1 = col[e + 4  + q];
        int c2 = col[e + 8  + q];
        int c3 = col[e + 12 + q];
        uint4 v0 = *(const uint4*)(h + (size_t)c0*128 + u*8);
        uint4 v1 = *(const uint4*)(h + (size_t)c1*128 + u*8);
        uint4 v2 = *(const uint4*)(h + (size_t)c2*128 + u*8);
        uint4 v3 = *(const uint4*)(h + (size_t)c3*128 + u*8);
        acc_u4(a, v0); acc_u4(a, v1); acc_u4(a, v2); acc_u4(a, v3);
    }
    // masked tail: up to 15 edges, all 4 loads issued for max memory parallelism
    if (e < end){
        int last = end - 1;
        int i0 = e + q, i1 = e + 4 + q, i2 = e + 8 + q, i3 = e + 12 + q;
        int c0 = col[min(i0, last)];
        int c1 = col[min(i1, last)];
        int c2 = col[min(i2, last)];
        int c3 = col[min(i3, last)];
        uint4 v0 = *(const uint4*)(h + (size_t)c0*128 + u*8);
        uint4 v1 = *(const uint4*)(h + (size_t)c1*128 + u*8);
        uint4 v2 = *(const uint4*)(h + (size_t)c2*128 + u*8);
        uint4 v3 = *(const uint4*)(h + (size_t)c3*128 + u*8);
        v0 = and4(v0, (i0 < end) ? 0xffffffffu : 0u);
        v1 = and4(v1, (i1 < end) ? 0xffffffffu : 0u);
        v2 = and4(v2, (i2 < end) ? 0xffffffffu : 0u);
        v3 = and4(v3, (i3 < end) ? 0xffffffffu : 0u);
        acc_u4(a, v0); acc_u4(a, v1); acc_u4(a, v2); acc_u4(a, v3);
    }
    #pragma unroll
    for (int j = 0; j < 8; ++j){
        a[j] += __shfl_xor(a[j], 16, 64);
        a[j] += __shfl_xor(a[j], 32, 64);
    }
    if (q == 0){
        float ep = 1.0f + eps[l];
        uint4 hs = *(const uint4*)(h + (size_t)n*128 + u*8);
        a[0] += ep * __builtin_bit_cast(float, hs.x << 16);
        a[1] += ep * __builtin_bit_cast(float, hs.x & 0xffff0000u);
        a[2] += ep * __builtin_bit_cast(float, hs.y << 16);
        a[3] += ep * __builtin_bit_cast(float, hs.y & 0xffff0000u);
        a[4] += ep * __builtin_bit_cast(float, hs.z << 16);
        a[5] += ep * __builtin_bit_cast(float, hs.z & 0xffff0000u);
        a[6] += ep * __builtin_bit_cast(float, hs.w << 16);
        a[7] += ep * __builtin_bit_cast(float, hs.w & 0xffff0000u);
        uint4 o;
        o.x = (unsigned)f2b(a[0]) | ((unsigned)f2b(a[1]) << 16);
        o.y = (unsigned)f2b(a[2]) | ((unsigned)f2b(a[3]) << 16);
        o.z = (unsigned)f2b(a[4]) | ((unsigned)f2b(a[5]) << 16);
        o.w = (unsigned)f2b(a[6]) | ((unsigned)f2b(a[7]) << 16);
        *(uint4*)(pooled + (size_t)n*128 + u*8) = o;
    }
}

// ---------------- A-fragment loader (16 rows, per-wave) ----------------
__device__ __forceinline__ void load_a(const unsigned short* __restrict__ Ain, int tile,
                                       int wv, int m, int q, bf16x8* dst){
    int node = tile*64 + wv*16 + m;
    bool valid = node < NN;
    const unsigned short* base = Ain + (size_t)(valid ? node : 0)*128 + q*8;
    #pragma unroll
    for (int kk = 0; kk < 4; ++kk){
        int4 v = *(const int4*)(base + kk*32);
        if (!valid) v = make_int4(0,0,0,0);
        dst[kk] = __builtin_bit_cast(bf16x8, v);
    }
}

// ---------------- MLP stage 1: Y = relu(g*(A@W+b)+bt), in-place, pipelined ----------------
__global__ __launch_bounds__(256, 4) void k_mlp1(const unsigned short* __restrict__ Ain,
                                                 unsigned short* __restrict__ Yout,
                                                 const unsigned short* __restrict__ Wf,
                                                 const float* __restrict__ bb, const float* __restrict__ gg,
                                                 const float* __restrict__ bt){
    __shared__ __align__(16) unsigned short Wl[16384];
    __shared__ __align__(16) unsigned short Ys[4][16*LDA];
    int t = threadIdx.x;
    int lane = t & 63, wv = t >> 6;
    int m = lane & 15, q = lane >> 4;
    for (int i = t; i < 2048; i += 256)
        *(int4*)(&Wl[i*8]) = *(const int4*)(Wf + i*8);
    __syncthreads();
    float ge[8], ce[8];
    #pragma unroll
    for (int j = 0; j < 8; ++j){
        int colc = j*16 + m;
        float gv = gg[colc];
        ge[j] = gv; ce[j] = bb[colc]*gv + bt[colc];
    }
    unsigned short* Y = &Ys[wv][0];
    int tile = blockIdx.x;
    bf16x8 aN[4];
    if (tile < NTILE64) load_a(Ain, tile, wv, m, q, aN);
    while (tile < NTILE64){
        bf16x8 a[4];
        #pragma unroll
        for (int kk = 0; kk < 4; ++kk) a[kk] = aN[kk];
        int nxt = tile + gridDim.x;
        if (nxt < NTILE64) load_a(Ain, nxt, wv, m, q, aN);   // prefetch next tile
        f32x4 acc[8];
        #pragma unroll
        for (int j = 0; j < 8; ++j) acc[j] = (f32x4){0.f,0.f,0.f,0.f};
        #pragma unroll
        for (int kk = 0; kk < 4; ++kk){
            #pragma unroll
            for (int j = 0; j < 8; ++j){
                bf16x8 b = *(const bf16x8*)(&Wl[((((j*4+kk)*4+q)*16)+m)*8]);
                acc[j] = __builtin_amdgcn_mfma_f32_16x16x32_bf16(a[kk], b, acc[j], 0, 0, 0);
            }
        }
        #pragma unroll
        for (int j = 0; j < 8; ++j){
            int colc = j*16 + m;
            #pragma unroll
            for (int r = 0; r < 4; ++r){
                float v = fmaxf(acc[j][r]*ge[j] + ce[j], 0.f);
                Y[(q*4 + r)*LDA + colc] = f2b(v);
            }
        }
        #pragma unroll
        for (int i = 0; i < 4; ++i){
            int idx = i*64 + lane;
            int r = idx >> 4, c = idx & 15;
            int nd = tile*64 + wv*16 + r;
            if (nd < NN)
                *(int4*)(Yout + (size_t)nd*128 + c*8) = *(const int4*)(&Y[r*LDA + c*8]);
        }
        tile = nxt;
    }
}

// ---------------- MLP stage 2: Out = relu(g*(Y@W+b)+bt) + fused graph pooling ----------------
__global__ __launch_bounds__(256, 4) void k_mlp2(const unsigned short* __restrict__ Ain,
                                                 unsigned short* __restrict__ Out,
                                                 const unsigned short* __restrict__ Wf,
                                                 const float* __restrict__ bb, const float* __restrict__ gg,
                                                 const float* __restrict__ bt,
                                                 float* __restrict__ Gout){
    __shared__ __align__(16) unsigned short Wl[16384];
    __shared__ __align__(16) unsigned short Ys[4][16*LDA];
    int t = threadIdx.x;
    int lane = t & 63, wv = t >> 6;
    int m = lane & 15, q = lane >> 4;
    for (int i = t; i < 2048; i += 256)
        *(int4*)(&Wl[i*8]) = *(const int4*)(Wf + i*8);
    __syncthreads();
    float ge[8], ce[8];
    #pragma unroll
    for (int j = 0; j < 8; ++j){
        int colc = j*16 + m;
        float gv = gg[colc];
        ge[j] = gv; ce[j] = bb[colc]*gv + bt[colc];
    }
    unsigned short* Y = &Ys[wv][0];
    int tile = blockIdx.x;
    bf16x8 aN[4];
    if (tile < NTILE64) load_a(Ain, tile, wv, m, q, aN);
    while (tile < NTILE64){
        bf16x8 a[4];
        #pragma unroll
        for (int kk = 0; kk < 4; ++kk) a[kk] = aN[kk];
        int nxt = tile + gridDim.x;
        if (nxt < NTILE64) load_a(Ain, nxt, wv, m, q, aN);
        f32x4 acc[8];
        #pragma unroll
        for (int j = 0; j < 8; ++j) acc[j] = (f32x4){0.f,0.f,0.f,0.f};
        #pragma unroll
        for (int kk = 0; kk < 4; ++kk){
            #pragma unroll
            for (int j = 0; j < 8; ++j){
                bf16x8 b = *(const bf16x8*)(&Wl[((((j*4+kk)*4+q)*16)+m)*8]);
                acc[j] = __builtin_amdgcn_mfma_f32_16x16x32_bf16(a[kk], b, acc[j], 0, 0, 0);
            }
        }
        #pragma unroll
        for (int j = 0; j < 8; ++j){
            int colc = j*16 + m;
            #pragma unroll
            for (int r = 0; r < 4; ++r){
                float v = fmaxf(acc[j][r]*ge[j] + ce[j], 0.f);
                Y[(q*4 + r)*LDA + colc] = f2b(v);
            }
        }
        int row0 = tile*64 + wv*16;
        #pragma unroll
        for (int i = 0; i < 4; ++i){
            int idx = i*64 + lane;
            int r = idx >> 4, c = idx & 15;
            int nd = row0 + r;
            if (nd < NN)
                *(int4*)(Out + (size_t)nd*128 + c*8) = *(const int4*)(&Y[r*LDA + c*8]);
        }
        // graph pooling: lane covers col pair (2*lane, 2*lane+1) over this wave's 16 rows
        {
            float run0 = 0.f, run1 = 0.f;
            int curg = row0 / GSZ;
            for (int r = 0; r < 16; ++r){
                int nd = row0 + r;
                if (nd >= NN) break;
                int g = nd / GSZ;
                if (g != curg){
                    if (run0 != 0.f) atomicAdd(&Gout[curg*128 + lane*2], run0);
                    if (run1 != 0.f) atomicAdd(&Gout[curg*128 + lane*2 + 1], run1);
                    run0 = 0.f; run1 = 0.f; curg = g;
                }
                unsigned int v = *(const unsigned int*)(&Y[r*LDA + lane*2]);
                run0 += b2f((unsigned short)v);
                run1 += b2f((unsigned short)(v >> 16));
            }
            if (run0 != 0.f) atomicAdd(&Gout[curg*128 + lane*2], run0);
            if (run1 != 0.f) atomicAdd(&Gout[curg*128 + lane*2 + 1], run1);
        }
        tile = nxt;
    }
}

// ---------------- score heads ----------------
__global__ __launch_bounds__(256) void k_score(const float* __restrict__ G,
                                               const float* __restrict__ W0, const float* __restrict__ b0,
                                               const float* __restrict__ Wk, const float* __restrict__ bk,
                                               float* __restrict__ out){
    int id = blockIdx.x*256 + threadIdx.x;
    if (id >= BB*OUTC) return;
    int b = id / OUTC, o = id % OUTC;
    float s = b0[o];
    #pragma unroll
    for (int k = 0; k < 4; ++k) s += bk[k*OUTC + o];
    const float* g0 = G + b*128;
    for (int c = 0; c < 128; ++c) s += g0[c] * W0[c*OUTC + o];
    for (int k = 0; k < 4; ++k){
        const float* gk = G + (size_t)(k+1)*BB*128 + b*128;
        const float* wk = Wk + k*128*OUTC;
        for (int c = 0; c < 128; ++c) s += gk[c] * wk[c*OUTC + o];
    }
    out[id] = s;
}

extern "C" void kernel_launch(void* const* d_in, const int* in_sizes, int n_in,
                              void* d_out, int out_size, void* d_ws, size_t ws_size,
                              hipStream_t stream){
    const float* node_features = (const float*)d_in[0];
    const int*   edge_src  = (const int*)d_in[1];
    const int*   edge_dst  = (const int*)d_in[2];
    const float* eps       = (const float*)d_in[4];
    const float* pre_W1    = (const float*)d_in[5];
    const float* pre_b1    = (const float*)d_in[6];
    const float* pre_g1    = (const float*)d_in[7];
    const float* pre_bt1   = (const float*)d_in[8];
    const float* pre_W2    = (const float*)d_in[9];
    const float* pre_b2    = (const float*)d_in[10];
    const float* pre_gout  = (const float*)d_in[11];
    const float* pre_btout = (const float*)d_in[12];
    const float* mlp_W1    = (const float*)d_in[13];
    const float* mlp_b1    = (const float*)d_in[14];
    const float* mlp_g1    = (const float*)d_in[15];
    const float* mlp_bt1   = (const float*)d_in[16];
    const float* mlp_W2    = (const float*)d_in[17];
    const float* mlp_b2    = (const float*)d_in[18];
    const float* bn_g      = (const float*)d_in[19];
    const float* bn_bt     = (const float*)d_in[20];
    const float* pred_W0   = (const float*)d_in[21];
    const float* pred_b0   = (const float*)d_in[22];
    const float* pred_W    = (const float*)d_in[23];
    const float* pred_b    = (const float*)d_in[24];
    float* out = (float*)d_out;

    char* p = (char*)d_ws;
    auto alloc = [&](size_t bytes)->char*{
        char* r = p;
        p += (bytes + 255) & ~(size_t)255;
        return r;
    };
    int* bucket_cursor    = (int*)alloc((size_t)NBKT*4);
    int* bucket_base      = (int*)alloc((size_t)(NBKT+1)*4);
    int* row_ptr          = (int*)alloc((size_t)(NN+1)*4);
    int* col              = (int*)alloc((size_t)EE*4);
    unsigned int* ebuf    = (unsigned int*)alloc((size_t)NBKT*BCAP*4);
    unsigned short* Wbf   = (unsigned short*)alloc((size_t)8*128*128*2);
    unsigned short* hA    = (unsigned short*)alloc((size_t)NN*128*2);
    unsigned short* hB    = (unsigned short*)alloc((size_t)NN*128*2);
    unsigned short* pooled= (unsigned short*)alloc((size_t)NN*128*2);
    float* G              = (float*)alloc((size_t)5*BB*128*4);

    hipMemsetAsync(bucket_cursor, 0, (size_t)NBKT*4, stream);

    // fused setup: blocks [0,391) bucket, [391,891) input, [891,1403) weight prep
    k_setup<<<NBUCKB + BB + 512, 256, 0, stream>>>(edge_src, edge_dst, bucket_cursor, ebuf,
                                                   node_features, hA, G,
                                                   pre_W1, pre_W2, mlp_W1, mlp_W2, Wbf);
    k_bscan<<<1, 1024, 0, stream>>>(bucket_cursor, bucket_base, row_ptr);
    k_csr<<<NBKT, 256, 0, stream>>>(bucket_cursor, bucket_base, ebuf, row_ptr, col);

    const unsigned short* hcur = hA;
    unsigned short* hnxt = hB;
    for (int l = 0; l < 4; ++l){
        k_agg<<<NN/4, 256, 0, stream>>>(row_ptr, col, hcur, eps, l, pooled);
        const unsigned short *W1t, *W2t;
        const float *b1,*g1,*bt1,*b2,*g2,*bt2;
        if (l == 0){
            W1t = Wbf;             W2t = Wbf + 16384;
            b1 = pre_b1; g1 = pre_g1; bt1 = pre_bt1;
            b2 = pre_b2; g2 = pre_gout; bt2 = pre_btout;
        } else {
            W1t = Wbf + (size_t)(2 + (l-1))*16384;
            W2t = Wbf + (size_t)(5 + (l-1))*16384;
            b1 = mlp_b1 + (l-1)*128; g1 = mlp_g1 + (l-1)*128; bt1 = mlp_bt1 + (l-1)*128;
            b2 = mlp_b2 + (l-1)*128; g2 = bn_g   + (l-1)*128; bt2 = bn_bt   + (l-1)*128;
        }
        k_mlp1<<<768, 256, 0, stream>>>(pooled, pooled, W1t, b1, g1, bt1);
        k_mlp2<<<768, 256, 0, stream>>>(pooled, hnxt, W2t, b2, g2, bt2,
                                        G + (size_t)(l+1)*BB*128);
        const unsigned short* tmp = hnxt;
        hnxt = (unsigned short*)hcur;
        hcur = tmp;
    }
    k_score<<<(BB*OUTC + 255)/256, 256, 0, stream>>>(G, pred_W0, pred_b0, pred_W, pred_b, out);
}